// Round 12
// baseline (376.103 us; speedup 1.0000x reference)
//
#include <hip/hip_runtime.h>
#include <hip/hip_bf16.h>

using bf16 = __hip_bfloat16;
typedef __attribute__((ext_vector_type(8))) short short8;
typedef __attribute__((ext_vector_type(4))) float f32x4;
typedef __attribute__((ext_vector_type(4))) unsigned int u32x4;

#define Bc 8
#define Tc 12
#define Nc 512
#define Dc 128
#define T_Hc 2
#define GEO_Hc 4
#define SEM_Hc 2
#define HDc 16
#define SCALEc 0.25f
#define LOG2E 1.4426950408889634f

// ================= ws layout =================
constexpr size_t TSZ = (size_t)Bc * Nc * T_Hc * Tc * HDc;      // 1,572,864
constexpr size_t GSZ = (size_t)Bc * Tc * GEO_Hc * Nc * HDc;    // 3,145,728
constexpr size_t SSZ = (size_t)Bc * Tc * SEM_Hc * Nc * HDc;    // 1,572,864
constexpr size_t CSZ = (size_t)Bc * Tc * Nc * Dc;              // 6,291,456
constexpr size_t H_TQ = 0;
constexpr size_t H_TK = H_TQ + TSZ;
constexpr size_t H_TV = H_TK + TSZ;
constexpr size_t H_GQ = H_TV + TSZ;
constexpr size_t H_GK = H_GQ + GSZ;
constexpr size_t H_GV = H_GK + GSZ;
constexpr size_t H_SQ = H_GV + GSZ;
constexpr size_t H_SK = H_SQ + SSZ;
constexpr size_t H_SV = H_SK + SSZ;
constexpr size_t H_CC = H_SV + SSZ;
constexpr size_t H_END = H_CC + CSZ;                           // 25,165,824 halves
constexpr size_t F_PK = (H_END + 1) / 2;
constexpr size_t F_PV = F_PK + 1024;
constexpr size_t F_FLAG = F_PV + 1024;
// bf16 weight copies for the MFMA GEMMs (≈ +0.23 MB):
constexpr size_t H_W2X = 2 * (F_FLAG + 64);    // [384][256] K2-duplicated
constexpr size_t H_W2O = H_W2X + 384 * 256;    // [128][128]
// bf16 masked-bias buffers (pre-scaled by log2e) overlay the dead T-QKV
// region (k_tattn runs first):
constexpr size_t H_BG = H_TQ;                  // geo: 8*512*512 halves
constexpr size_t H_BS = H_TQ + 2097152;        // sem: 512*512 halves
// ws need ~50.6 MB

__device__ __forceinline__ float b2f(bf16 v) { return __bfloat162float(v); }
__device__ __forceinline__ bf16 f2b(float v) { return __float2bfloat16(v); }
__device__ __forceinline__ short f2bs(float v) {
    bf16 b = __float2bfloat16(v);
    return *reinterpret_cast<short*>(&b);
}
__device__ __forceinline__ float bs2f(short s) {
    union { unsigned u; float f; } x;
    x.u = ((unsigned)(unsigned short)s) << 16;
    return x.f;
}
__device__ __forceinline__ unsigned packbf(float a, float b) {
    unsigned ua = (unsigned)(unsigned short)f2bs(a);
    unsigned ub = (unsigned)(unsigned short)f2bs(b);
    return ua | (ub << 16);
}
__device__ __forceinline__ float exp2hw(float x) {   // 2^x via v_exp_f32
    float r;
    asm("v_exp_f32 %0, %1" : "=v"(r) : "v"(x));
    return r;
}
__device__ __forceinline__ float rcphw(float x) {    // ~1/x via v_rcp_f32
    float r;
    asm("v_rcp_f32 %0, %1" : "=v"(r) : "v"(x));
    return r;
}

// channel -> weight-row pointer for the 384-ch concat GEMM
__device__ __forceinline__ const float* wrow(
    int gc, const float* tq, const float* tk, const float* tv,
    const float* gq, const float* gk, const float* gv,
    const float* sq, const float* sk, const float* sv) {
    if (gc < 32) return tq + (size_t)gc * 128;
    if (gc < 64) return tk + (size_t)(gc - 32) * 128;
    if (gc < 96) return tv + (size_t)(gc - 64) * 128;
    if (gc < 160) return gq + (size_t)(gc - 96) * 128;
    if (gc < 224) return gk + (size_t)(gc - 160) * 128;
    if (gc < 288) return gv + (size_t)(gc - 224) * 128;
    if (gc < 320) return sq + (size_t)(gc - 288) * 128;
    if (gc < 352) return sk + (size_t)(gc - 320) * 128;
    return sv + (size_t)(gc - 352) * 128;
}

// ---- kernel: MERGED weight conversion + pattern k/v proj + mask detect ----
// blocks 0..255: W2X/W2O bf16 conversion (geo/sem-q rows pre-scaled by
// SCALE*log2e). blocks 256..263: pattern k/v projection into fws.
// block 264: RUNTIME mask dtype detection (byte-pattern sniff) -> fws[F_FLAG].
__global__ __launch_bounds__(256) void k_prepw(
    const float* __restrict__ t_qw, const float* __restrict__ t_kw,
    const float* __restrict__ t_vw, const float* __restrict__ geo_qw,
    const float* __restrict__ geo_kw, const float* __restrict__ geo_vw,
    const float* __restrict__ sem_qw, const float* __restrict__ sem_kw,
    const float* __restrict__ sem_vw, const float* __restrict__ proj_w,
    const float* __restrict__ pattern_keys, const float* __restrict__ pat_kw,
    const float* __restrict__ pat_kb, const float* __restrict__ pat_vw,
    const float* __restrict__ pat_vb, const unsigned char* __restrict__ mask,
    bf16* __restrict__ hb, float* __restrict__ fws) {
    if (blockIdx.x < 256) {
        int gid = blockIdx.x * 256 + threadIdx.x;   // 0..65535
        if (gid < 49152) {
            int row = gid >> 7, k = gid & 127;
            const float* src = wrow(row, t_qw, t_kw, t_vw, geo_qw, geo_kw,
                                    geo_vw, sem_qw, sem_kw, sem_vw);
            float v = src[k];
            if ((row >= 96 && row < 160) || (row >= 288 && row < 320))
                v *= SCALEc * LOG2E;
            bf16 bv = f2b(v);
            hb[H_W2X + (size_t)row * 256 + 2 * k] = bv;
            hb[H_W2X + (size_t)row * 256 + 2 * k + 1] = bv;
        } else {
            int g = gid - 49152;
            hb[H_W2O + g] = f2b(proj_w[g]);
        }
    } else if (blockIdx.x < 264) {
        int idx = (blockIdx.x - 256) * 256 + threadIdx.x;   // 0..2047
        int which = idx >> 10;
        int r = idx & 1023;
        int k = r >> 6, e = r & 63;
        const float4* w = (const float4*)((which ? pat_vw : pat_kw) + (size_t)e * 128);
        const float4* pk = (const float4*)(pattern_keys + (size_t)k * 128);
        float acc = which ? pat_vb[e] : pat_kb[e];
#pragma unroll
        for (int j = 0; j < 32; ++j) {
            float4 a = pk[j], b = w[j];
            acc = fmaf(a.x, b.x, acc); acc = fmaf(a.y, b.y, acc);
            acc = fmaf(a.z, b.z, acc); acc = fmaf(a.w, b.w, acc);
        }
        fws[(which ? F_PV : F_PK) + (size_t)k * 64 + e] = acc;
    } else {
        __shared__ int s_u8, s_odd4;
        int tid = threadIdx.x;
        if (tid == 0) { s_u8 = 0; s_odd4 = 0; }
        __syncthreads();
        int u8 = 0, odd4 = 0;
        for (int i = tid * 16; i < tid * 16 + 16; ++i) {
            unsigned char v = mask[i];
            if (v && (i & 3)) u8 = 1;
            if (v && ((i & 7) == 4)) odd4 = 1;
        }
        if (u8) atomicOr(&s_u8, 1);
        if (odd4) atomicOr(&s_odd4, 1);
        __syncthreads();
        if (tid == 0) fws[F_FLAG] = s_u8 ? 0.f : (s_odd4 ? 1.f : 2.f);
    }
}

// ---- kernel: build masked-bias buffers (bf16, pre-scaled by log2e) --------
__global__ __launch_bounds__(256) void k_bias(
    const float* __restrict__ dyn, const unsigned char* __restrict__ gm,
    const unsigned char* __restrict__ sm, const float* __restrict__ fws,
    bf16* __restrict__ hb) {
    int bid = blockIdx.x;
    int tid = threadIdx.x;
    int mode = (int)fws[F_FLAG];
    if (bid < 8192) {
        int b = bid & 7;
        int inner = bid >> 3;                         // 0..1023
        size_t rem = (size_t)inner * 256 + tid;       // q*512+k, 0..262143
        size_t gid = (size_t)b * 262144 + rem;
        int mv = (mode == 0) ? (int)gm[rem]
               : (mode == 1) ? ((const int*)gm)[rem]
                             : ((const int*)gm)[2 * rem];
        hb[H_BG + gid] = f2b(mv ? -1.44e30f : dyn[gid] * LOG2E);
    } else {
        size_t sid = (size_t)(bid - 8192) * 256 + tid;
        int mv = (mode == 0) ? (int)sm[sid]
               : (mode == 1) ? ((const int*)sm)[sid]
                             : ((const int*)sm)[2 * sid];
        hb[H_BS + sid] = f2b(mv ? -1.44e30f : 0.f);
    }
}

// ---- kernel: FUSED projection GEMM + pattern attention --------------------
// Per block: 128 tokens. Phase A: stage xp f32 into xs, pq-GEMM (pat_qw from
// global, L1-hot), pq->xs, logits vs F_PK + softmax + output vs F_PV into
// 16 KB pat LDS (bf16, short4-swizzled). Phase B: X hi/lo bf16 GEMM as
// before; GK epilogue adds pat -> geo_k written ONCE (k_projp eliminated).
// LDS 64+16 = 80 KB -> exactly 2 blocks/CU.
__global__ __launch_bounds__(256, 2) void k_projx(
    const float* __restrict__ x, const float* __restrict__ xp,
    const float* __restrict__ pat_qw, const float* __restrict__ pat_qb,
    const float* __restrict__ fws, bf16* __restrict__ hb) {
    __shared__ short xs[128 * 256];   // 64 KB
    __shared__ short pat[128 * 64];   // 16 KB, bf16, short4 granule swizzle

    int tid = threadIdx.x;
    int m0 = blockIdx.x * 128;
    int b = m0 / (Tc * Nc);
    int rr = m0 - b * Tc * Nc;
    int t = rr >> 9;
    int n0 = rr & 511;

    // ---- phase A1: stage xp f32 (swizzled float4 granules) ----
    float* xpf = (float*)xs;
    for (int u = tid; u < 4096; u += 256) {
        int row = u >> 5, g = u & 31;
        *(float4*)&xpf[row * 128 + ((g ^ (row & 7)) << 2)] =
            *(const float4*)(xp + (size_t)(m0 + row) * 128 + g * 4);
    }
    __syncthreads();

    // ---- phase A2: pq GEMM [128 tok]x[64 e] ----
    int ty = tid >> 4, tx = tid & 15;
    float pacc[8][4];
#pragma unroll
    for (int i = 0; i < 8; ++i)
#pragma unroll
        for (int j = 0; j < 4; ++j) pacc[i][j] = 0.f;
    for (int kk = 0; kk < 128; kk += 4) {
        int g = kk >> 2;
        float4 bv[4];
#pragma unroll
        for (int j = 0; j < 4; ++j)
            bv[j] = *(const float4*)(pat_qw + (size_t)(tx + 16 * j) * 128 + kk);
#pragma unroll
        for (int i = 0; i < 8; ++i) {
            int row = ty + 16 * i;
            float4 av = *(const float4*)&xpf[row * 128 + ((g ^ (row & 7)) << 2)];
#pragma unroll
            for (int j = 0; j < 4; ++j) {
                pacc[i][j] = fmaf(av.x, bv[j].x, pacc[i][j]);
                pacc[i][j] = fmaf(av.y, bv[j].y, pacc[i][j]);
                pacc[i][j] = fmaf(av.z, bv[j].z, pacc[i][j]);
                pacc[i][j] = fmaf(av.w, bv[j].w, pacc[i][j]);
            }
        }
    }
    __syncthreads();
    // store pq -> xs as f32 [128][69]
    float* pqs = (float*)xs;
    {
        float qb[4];
#pragma unroll
        for (int j = 0; j < 4; ++j) qb[j] = pat_qb[tx + 16 * j];
#pragma unroll
        for (int i = 0; i < 8; ++i)
#pragma unroll
            for (int j = 0; j < 4; ++j)
                pqs[(ty + 16 * i) * 69 + tx + 16 * j] = pacc[i][j] + qb[j];
    }
    __syncthreads();

    // ---- phase A3: logits + softmax + pattern output (2 threads/token) ----
    {
        int tok = tid >> 1, hf = tid & 1;
        float lg[8];
#pragma unroll
        for (int k = 0; k < 8; ++k) lg[k] = 0.f;
        for (int e = 0; e < 64; ++e) {
            float q = pqs[tok * 69 + e];
#pragma unroll
            for (int k = 0; k < 8; ++k)
                lg[k] = fmaf(q, fws[F_PK + (size_t)(hf * 8 + k) * 64 + e], lg[k]);
        }
#pragma unroll
        for (int k = 0; k < 8; ++k) lg[k] *= SCALEc;
        float mx = lg[0];
#pragma unroll
        for (int k = 1; k < 8; ++k) mx = fmaxf(mx, lg[k]);
        mx = fmaxf(mx, __shfl_xor(mx, 1));
        float pown[8], sown = 0.f;
#pragma unroll
        for (int k = 0; k < 8; ++k) {
            pown[k] = __expf(lg[k] - mx);
            sown += pown[k];
        }
        float inv = 1.f / (sown + __shfl_xor(sown, 1));
        float poth[8];
#pragma unroll
        for (int k = 0; k < 8; ++k) poth[k] = __shfl_xor(pown[k], 1);
        // channels c = hf*32 .. hf*32+31, write as short4 (swizzled granules)
#pragma unroll
        for (int g4 = 0; g4 < 8; ++g4) {
            short4 st;
            float vv[4];
#pragma unroll
            for (int el = 0; el < 4; ++el) {
                int c = hf * 32 + g4 * 4 + el;
                float v = 0.f;
#pragma unroll
                for (int k = 0; k < 8; ++k) {
                    v = fmaf(pown[k], fws[F_PV + (size_t)(hf * 8 + k) * 64 + c], v);
                    v = fmaf(poth[k], fws[F_PV + (size_t)((1 - hf) * 8 + k) * 64 + c], v);
                }
                vv[el] = v * inv;
            }
            st.x = f2bs(vv[0]); st.y = f2bs(vv[1]);
            st.z = f2bs(vv[2]); st.w = f2bs(vv[3]);
            int g = hf * 8 + g4;
            *(short4*)&pat[tok * 64 + ((g ^ (tok & 7)) << 2)] = st;
        }
    }
    __syncthreads();

    // ---- phase B: stage + convert X tile: fp32 -> interleaved hi/lo bf16 --
    for (int u = tid; u < 4096; u += 256) {
        int row = u >> 5, g = u & 31;
        float4 v = *(const float4*)(x + (size_t)(m0 + row) * 128 + g * 4);
        short8 s;
        short h0 = f2bs(v.x); s[0] = h0; s[1] = f2bs(v.x - bs2f(h0));
        short h1 = f2bs(v.y); s[2] = h1; s[3] = f2bs(v.y - bs2f(h1));
        short h2 = f2bs(v.z); s[4] = h2; s[5] = f2bs(v.z - bs2f(h2));
        short h3 = f2bs(v.w); s[6] = h3; s[7] = f2bs(v.w - bs2f(h3));
        *(short8*)&xs[row * 256 + ((g ^ (row & 7)) << 3)] = s;
    }
    __syncthreads();

    int w = tid >> 6;
    int lane = tid & 63;
    int l15 = lane & 15;
    int quad = lane >> 4;
    const bf16* w2 = hb + H_W2X;

    for (int nc = 0; nc < 6; ++nc) {
        f32x4 acc[2][4];
#pragma unroll
        for (int i = 0; i < 2; ++i)
#pragma unroll
            for (int j = 0; j < 4; ++j) acc[i][j] = (f32x4){0.f, 0.f, 0.f, 0.f};

#pragma unroll
        for (int ks = 0; ks < 8; ++ks) {
            int r0 = w * 32 + l15;
            int r1 = r0 + 16;
            short8 a0 = *(const short8*)&xs[r0 * 256 + (((ks * 4 + quad) ^ (r0 & 7)) << 3)];
            short8 a1 = *(const short8*)&xs[r1 * 256 + (((ks * 4 + quad) ^ (r1 & 7)) << 3)];
#pragma unroll
            for (int nj = 0; nj < 4; ++nj) {
                short8 bfr = *(const short8*)(w2 + (size_t)(nc * 64 + nj * 16 + l15) * 256
                                              + ks * 32 + quad * 8);
                acc[0][nj] = __builtin_amdgcn_mfma_f32_16x16x32_bf16(a0, bfr, acc[0][nj], 0, 0, 0);
                acc[1][nj] = __builtin_amdgcn_mfma_f32_16x16x32_bf16(a1, bfr, acc[1][nj], 0, 0, 0);
            }
        }
        // epilogue scatter (D: row=token via quad*4+r, col=channel via l15)
#pragma unroll
        for (int nj = 0; nj < 4; ++nj) {
            int gc = nc * 64 + nj * 16 + l15;
            int tile16 = nc * 4 + nj;
            int d = gc & 15;
#pragma unroll
            for (int i = 0; i < 2; ++i) {
                int nrow0 = n0 + w * 32 + i * 16 + quad * 4;
#pragma unroll
                for (int r = 0; r < 4; ++r) {
                    int n = nrow0 + r;
                    float v = acc[i][nj][r];
                    size_t idx;
                    if (tile16 < 6) {
                        int which = gc >> 5, hh = (gc >> 4) & 1;
                        size_t base = which == 0 ? H_TQ : which == 1 ? H_TK : H_TV;
                        idx = base + ((size_t)(b * Nc + n) * T_Hc + hh) * (Tc * HDc)
                              + t * HDc + d;
                    } else if (tile16 < 18) {
                        int r2 = gc - 96;
                        int which = r2 >> 6, hh = (r2 >> 4) & 3;
                        size_t base = which == 0 ? H_GQ : which == 1 ? H_GK : H_GV;
                        size_t sl = (((size_t)b * Tc + t) * GEO_Hc + hh) * (Nc * HDc);
                        if (which == 1) {   // geo_k: add pattern contribution
                            int c = gc - 160;
                            int lr = w * 32 + i * 16 + quad * 4 + r;
                            v += bs2f(pat[lr * 64
                                   + ((((c >> 2) ^ (lr & 7)) << 2) | (c & 3))]);
                        }
                        idx = base + sl + (which == 2 ? ((size_t)d * Nc + n)
                                                      : ((size_t)n * HDc + d));
                    } else {
                        int r2 = gc - 288;
                        int which = r2 >> 5, hh = (r2 >> 4) & 1;
                        size_t base = which == 0 ? H_SQ : which == 1 ? H_SK : H_SV;
                        size_t sl = (((size_t)b * Tc + t) * SEM_Hc + hh) * (Nc * HDc);
                        idx = base + sl + (which == 2 ? ((size_t)d * Nc + n)
                                                      : ((size_t)n * HDc + d));
                    }
                    hb[idx] = f2b(v);
                }
            }
        }
    }
}

// ---- kernel: temporal attention, 4 units per 256-thread block -------------
__global__ __launch_bounds__(256, 8) void k_tattn(bf16* __restrict__ hb) {
    __shared__ float q[4][192], kkv[4][192], vv[4][192], ss[4][144];
    int unit = threadIdx.x >> 6;
    int tid = threadIdx.x & 63;
    int blk = blockIdx.x * 4 + unit;
    int h = blk & 1;
    int bn = blk >> 1;
    int b = bn >> 9;
    int n = bn & 511;
    size_t base = ((size_t)(b * Nc + n) * T_Hc + h) * (Tc * HDc);

    for (int u = tid; u < 192; u += 64) {
        q[unit][u] = b2f(hb[H_TQ + base + u]);
        kkv[unit][u] = b2f(hb[H_TK + base + u]);
        vv[unit][u] = b2f(hb[H_TV + base + u]);
    }
    __syncthreads();
    for (int idx = tid; idx < 144; idx += 64) {
        int qi = idx / 12, ki = idx - qi * 12;
        float acc = 0.f;
#pragma unroll
        for (int d = 0; d < 16; ++d)
            acc = fmaf(q[unit][qi * 16 + d], kkv[unit][ki * 16 + d], acc);
        ss[unit][idx] = acc * SCALEc;
    }
    __syncthreads();
    if (tid < 12) {
        float mx = -1e30f;
        for (int ki = 0; ki < 12; ++ki) mx = fmaxf(mx, ss[unit][tid * 12 + ki]);
        float sum = 0.f;
        for (int ki = 0; ki < 12; ++ki) {
            float p = __expf(ss[unit][tid * 12 + ki] - mx);
            ss[unit][tid * 12 + ki] = p;
            sum += p;
        }
        float inv = 1.f / sum;
        for (int ki = 0; ki < 12; ++ki) ss[unit][tid * 12 + ki] *= inv;
    }
    __syncthreads();
    for (int idx = tid; idx < 192; idx += 64) {
        int qi = idx >> 4, d = idx & 15;
        float acc = 0.f;
#pragma unroll
        for (int ki = 0; ki < 12; ++ki)
            acc = fmaf(ss[unit][qi * 12 + ki], vv[unit][ki * 16 + d], acc);
        hb[H_CC + (((size_t)b * Tc + qi) * Nc + n) * Dc + h * HDc + d] = f2b(acc);
    }
}

// ---- kernel: MERGED MFMA spatial attention (geo + sem), S^T formulation ---
// v6: bf16 bias (log2e pre-scaled), exp2 logits, setprio around PV, rcp
// normalize. q-tile 64/block, grid 4608, launch_bounds(256,8), direct exp,
// shfl P-exchange, vt-only LDS (16 KB).
// Work mapping: bid&7 = b (XCD axis) -> balanced XCDs, b-local L2 read set.
__global__ __launch_bounds__(256, 8) void k_attn2m(bf16* __restrict__ hb) {
    __shared__ short vt[16 * 512];       // 16 KB, V^T rows d, swizzled granules

    int bid = blockIdx.x;                // 0..4607
    int b = bid & 7;                     // XCD-aligned batch index
    int rem = bid >> 3;                  // 0..575 per-b work id
    int m3 = rem % 3;
    int d3 = rem / 3;                    // 0..191

    int H, coff, lb;
    size_t QO, KO, VO, bstride;
    const bf16* bias0;
    if (m3 == 2) {                       // semantic work: lb in [0,192)
        H = SEM_Hc; coff = 96; QO = H_SQ; KO = H_SK; VO = H_SV;
        bias0 = hb + H_BS; bstride = 0; lb = d3;
    } else {                             // geo work: lb = 2*d3+m3 in [0,384)
        H = GEO_Hc; coff = 32; QO = H_GQ; KO = H_GK; VO = H_GV;
        bias0 = hb + H_BG; bstride = (size_t)Nc * Nc; lb = 2 * d3 + m3;
    }
    int part = lb & 7;                   // q-tile index (64 rows)
    int th = lb >> 3;
    int h = th % H;
    int t = th / H;

    size_t bth = (((size_t)b * Tc + t) * H + h) * (size_t)(Nc * HDc);
    const bf16* Qp = hb + QO + bth;
    const bf16* Kp = hb + KO + bth;
    const bf16* Vg = hb + VO + bth;      // transposed: [16][512]
    const bf16* bp = bias0 + (size_t)b * bstride;

    int tid = threadIdx.x;

    // stage V^T: straight coalesced copy, granule XOR-swizzle on LDS write
    for (int u = tid; u < 1024; u += 256) {
        int d = u >> 6, gg = u & 63;
        *(short8*)&vt[d * 512 + ((gg ^ (d & 7)) << 3)] =
            *(const short8*)(Vg + (size_t)d * 512 + gg * 8);
    }
    __syncthreads();

    int lane = tid & 63;
    int w = tid >> 6;
    int l15 = lane & 15;
    int quad = lane >> 4;
    int sw = l15 & 7;
    // shfl exchange geometry: target (l15,quad) pulls P words from lanes
    // srcA = l15 + 32*(quad&1) and srcB = srcA+16, at kt = 2*kw + (quad>>1).
    int srcA = l15 + ((lane & 16) << 1);
    int srcB = srcA + 16;
    bool hi = lane >= 32;

    union U8 { u32x4 u; short8 s; };

    int q0 = part * 64 + w * 16;
    int qg = q0 + l15;
    short8 bq = {0, 0, 0, 0, 0, 0, 0, 0};
    if (quad < 2) bq = *(const short8*)(Qp + (size_t)qg * 16 + quad * 8);

    float l_i = 0.f;
    f32x4 O = {0.f, 0.f, 0.f, 0.f};

    for (int ch = 0; ch < 4; ++ch) {
        int kabs0 = ch * 128;
        f32x4 S[8];
#pragma unroll
        for (int kt = 0; kt < 8; ++kt) {
            int kabs = kabs0 + kt * 16;
            short4 bb = *(const short4*)(bp + (size_t)qg * 512 + kabs + quad * 4);
            f32x4 c;
            c[0] = bs2f(bb.x); c[1] = bs2f(bb.y);
            c[2] = bs2f(bb.z); c[3] = bs2f(bb.w);
            short8 ak = {0, 0, 0, 0, 0, 0, 0, 0};
            if (quad < 2)
                ak = *(const short8*)(Kp + (size_t)(kabs + l15) * 16 + quad * 8);
            S[kt] = __builtin_amdgcn_mfma_f32_16x16x32_bf16(ak, bq, c, 0, 0, 0);
        }
        // logits pre-scaled by log2e -> raw v_exp_f32 (2^x); masked bias
        // = -1.44e30 -> 0. No max tracking (data bounded).
        unsigned pk2[8][2];
        float psum = 0.f;
#pragma unroll
        for (int kt = 0; kt < 8; ++kt) {
            float p0 = exp2hw(S[kt][0]);
            float p1 = exp2hw(S[kt][1]);
            float p2 = exp2hw(S[kt][2]);
            float p3 = exp2hw(S[kt][3]);
            psum += (p0 + p1) + (p2 + p3);
            pk2[kt][0] = packbf(p0, p1);
            pk2[kt][1] = packbf(p2, p3);
        }
        psum += __shfl_xor(psum, 16);
        psum += __shfl_xor(psum, 32);
        l_i += psum;
        __builtin_amdgcn_s_setprio(1);
#pragma unroll
        for (int kw = 0; kw < 4; ++kw) {
            unsigned eA0 = __shfl(pk2[2 * kw][0], srcA);
            unsigned eA1 = __shfl(pk2[2 * kw][1], srcA);
            unsigned oA0 = __shfl(pk2[2 * kw + 1][0], srcA);
            unsigned oA1 = __shfl(pk2[2 * kw + 1][1], srcA);
            unsigned eB0 = __shfl(pk2[2 * kw][0], srcB);
            unsigned eB1 = __shfl(pk2[2 * kw][1], srcB);
            unsigned oB0 = __shfl(pk2[2 * kw + 1][0], srcB);
            unsigned oB1 = __shfl(pk2[2 * kw + 1][1], srcB);
            U8 ap;
            ap.u = (u32x4){hi ? oA0 : eA0, hi ? oA1 : eA1,
                           hi ? oB0 : eB0, hi ? oB1 : eB1};
            short8 bv = *(const short8*)&vt[l15 * 512
                             + (((ch * 16 + kw * 4 + quad) ^ sw) << 3)];
            O = __builtin_amdgcn_mfma_f32_16x16x32_bf16(ap.s, bv, O, 0, 0, 0);
        }
        __builtin_amdgcn_s_setprio(0);
    }
    float li0 = __shfl(l_i, (quad << 2) | 0);
    float li1 = __shfl(l_i, (quad << 2) | 1);
    float li2 = __shfl(l_i, (quad << 2) | 2);
    float li3 = __shfl(l_i, (quad << 2) | 3);
    size_t obase = H_CC + (((size_t)b * Tc + t) * Nc + q0) * Dc + coff + h * HDc + l15;
    hb[obase + (size_t)(quad * 4 + 0) * Dc] = f2b(O[0] * rcphw(li0));
    hb[obase + (size_t)(quad * 4 + 1) * Dc] = f2b(O[1] * rcphw(li1));
    hb[obase + (size_t)(quad * 4 + 2) * Dc] = f2b(O[2] * rcphw(li2));
    hb[obase + (size_t)(quad * 4 + 3) * Dc] = f2b(O[3] * rcphw(li3));
}

// ---- kernel: MFMA output projection CC(49152x128) @ proj_w^T --------------
__global__ __launch_bounds__(256, 3) void k_outm(
    const bf16* __restrict__ hb, const float* __restrict__ proj_b,
    float* __restrict__ out) {
    __shared__ short cs[128 * 128];   // 32 KB, swizzled granules
    __shared__ float pbs[128];

    int tid = threadIdx.x;
    int m0 = blockIdx.x * 128;

    for (int u = tid; u < 2048; u += 256) {
        int row = u >> 4, g = u & 15;
        *(short8*)&cs[row * 128 + ((g ^ (row & 7)) << 3)] =
            *(const short8*)(hb + H_CC + (size_t)(m0 + row) * 128 + g * 8);
    }
    if (tid < 128) pbs[tid] = proj_b[tid];
    __syncthreads();

    int w = tid >> 6;
    int lane = tid & 63;
    int l15 = lane & 15;
    int quad = lane >> 4;
    const bf16* w2o = hb + H_W2O;

    f32x4 acc[2][8];
#pragma unroll
    for (int i = 0; i < 2; ++i)
#pragma unroll
        for (int j = 0; j < 8; ++j) acc[i][j] = (f32x4){0.f, 0.f, 0.f, 0.f};

#pragma unroll
    for (int ks = 0; ks < 4; ++ks) {
        int r0 = w * 32 + l15;
        int r1 = r0 + 16;
        short8 a0 = *(const short8*)&cs[r0 * 128 + (((ks * 4 + quad) ^ (r0 & 7)) << 3)];
        short8 a1 = *(const short8*)&cs[r1 * 128 + (((ks * 4 + quad) ^ (r1 & 7)) << 3)];
#pragma unroll
        for (int nj = 0; nj < 8; ++nj) {
            short8 bfr = *(const short8*)(w2o + (size_t)(nj * 16 + l15) * 128
                                          + ks * 32 + quad * 8);
            acc[0][nj] = __builtin_amdgcn_mfma_f32_16x16x32_bf16(a0, bfr, acc[0][nj], 0, 0, 0);
            acc[1][nj] = __builtin_amdgcn_mfma_f32_16x16x32_bf16(a1, bfr, acc[1][nj], 0, 0, 0);
        }
    }
#pragma unroll
    for (int i = 0; i < 2; ++i) {
#pragma unroll
        for (int nj = 0; nj < 8; ++nj) {
            int ch = nj * 16 + l15;
            float bias = pbs[ch];
#pragma unroll
            for (int r = 0; r < 4; ++r) {
                int token = m0 + w * 32 + i * 16 + quad * 4 + r;
                out[(size_t)token * 128 + ch] = acc[i][nj][r] + bias;
            }
        }
    }
}

extern "C" void kernel_launch(void* const* d_in, const int* in_sizes, int n_in,
                              void* d_out, int out_size, void* d_ws, size_t ws_size,
                              hipStream_t stream) {
    const float* x = (const float*)d_in[0];
    const float* xp = (const float*)d_in[1];
    const float* pattern_keys = (const float*)d_in[2];
    const float* dyn = (const float*)d_in[3];
    const void* geo_mask = d_in[4];
    const void* sem_mask = d_in[5];
    const float* t_qw = (const float*)d_in[6];
    const float* t_kw = (const float*)d_in[7];
    const float* t_vw = (const float*)d_in[8];
    const float* geo_qw = (const float*)d_in[9];
    const float* geo_kw = (const float*)d_in[10];
    const float* geo_vw = (const float*)d_in[11];
    const float* sem_qw = (const float*)d_in[12];
    const float* sem_kw = (const float*)d_in[13];
    const float* sem_vw = (const float*)d_in[14];
    const float* pat_qw = (const float*)d_in[15];
    const float* pat_qb = (const float*)d_in[16];
    const float* pat_kw = (const float*)d_in[17];
    const float* pat_kb = (const float*)d_in[18];
    const float* pat_vw = (const float*)d_in[19];
    const float* pat_vb = (const float*)d_in[20];
    const float* proj_w = (const float*)d_in[21];
    const float* proj_b = (const float*)d_in[22];

    bf16* hb = (bf16*)d_ws;
    float* fws = (float*)d_ws;

    k_prepw<<<265, 256, 0, stream>>>(t_qw, t_kw, t_vw, geo_qw, geo_kw, geo_vw,
                                     sem_qw, sem_kw, sem_vw, proj_w,
                                     pattern_keys, pat_kw, pat_kb, pat_vw,
                                     pat_vb, (const unsigned char*)geo_mask,
                                     hb, fws);
    k_projx<<<384, 256, 0, stream>>>(x, xp, pat_qw, pat_qb, fws, hb);
    k_tattn<<<2048, 256, 0, stream>>>(hb);
    k_bias<<<9216, 256, 0, stream>>>(dyn, (const unsigned char*)geo_mask,
                                     (const unsigned char*)sem_mask, fws, hb);
    k_attn2m<<<Bc * Tc * (GEO_Hc + SEM_Hc) * 8, 256, 0, stream>>>(hb);
    k_outm<<<384, 256, 0, stream>>>(hb, proj_b, (float*)d_out);
}

// Round 13
// 337.692 us; speedup vs baseline: 1.1137x; 1.1137x over previous
//
#include <hip/hip_runtime.h>
#include <hip/hip_bf16.h>

using bf16 = __hip_bfloat16;
typedef __attribute__((ext_vector_type(8))) short short8;
typedef __attribute__((ext_vector_type(4))) float f32x4;
typedef __attribute__((ext_vector_type(4))) unsigned int u32x4;

#define Bc 8
#define Tc 12
#define Nc 512
#define Dc 128
#define T_Hc 2
#define GEO_Hc 4
#define SEM_Hc 2
#define HDc 16
#define SCALEc 0.25f
#define LOG2E 1.4426950408889634f

// ================= ws layout =================
constexpr size_t TSZ = (size_t)Bc * Nc * T_Hc * Tc * HDc;      // 1,572,864
constexpr size_t GSZ = (size_t)Bc * Tc * GEO_Hc * Nc * HDc;    // 3,145,728
constexpr size_t SSZ = (size_t)Bc * Tc * SEM_Hc * Nc * HDc;    // 1,572,864
constexpr size_t CSZ = (size_t)Bc * Tc * Nc * Dc;              // 6,291,456
constexpr size_t H_TQ = 0;
constexpr size_t H_TK = H_TQ + TSZ;
constexpr size_t H_TV = H_TK + TSZ;
constexpr size_t H_GQ = H_TV + TSZ;
constexpr size_t H_GK = H_GQ + GSZ;
constexpr size_t H_GV = H_GK + GSZ;
constexpr size_t H_SQ = H_GV + GSZ;
constexpr size_t H_SK = H_SQ + SSZ;
constexpr size_t H_SV = H_SK + SSZ;
constexpr size_t H_CC = H_SV + SSZ;
constexpr size_t H_END = H_CC + CSZ;                           // 25,165,824 halves
constexpr size_t F_PK = (H_END + 1) / 2;
constexpr size_t F_PV = F_PK + 1024;
constexpr size_t F_FLAG = F_PV + 1024;
// bf16 weight copies for the MFMA GEMMs (≈ +0.23 MB):
constexpr size_t H_W2X = 2 * (F_FLAG + 64);    // [384][256] K2-duplicated
constexpr size_t H_W2O = H_W2X + 384 * 256;    // [128][128]
// bf16 masked-bias buffers (pre-scaled by log2e) overlay the dead T-QKV
// region (k_tattn runs first):
constexpr size_t H_BG = H_TQ;                  // geo: 8*512*512 halves
constexpr size_t H_BS = H_TQ + 2097152;        // sem: 512*512 halves
// ws need ~50.6 MB

__device__ __forceinline__ float b2f(bf16 v) { return __bfloat162float(v); }
__device__ __forceinline__ bf16 f2b(float v) { return __float2bfloat16(v); }
__device__ __forceinline__ short f2bs(float v) {
    bf16 b = __float2bfloat16(v);
    return *reinterpret_cast<short*>(&b);
}
__device__ __forceinline__ float bs2f(short s) {
    union { unsigned u; float f; } x;
    x.u = ((unsigned)(unsigned short)s) << 16;
    return x.f;
}
__device__ __forceinline__ unsigned packbf(float a, float b) {
    unsigned ua = (unsigned)(unsigned short)f2bs(a);
    unsigned ub = (unsigned)(unsigned short)f2bs(b);
    return ua | (ub << 16);
}
__device__ __forceinline__ float exp2hw(float x) {   // 2^x via v_exp_f32
    float r;
    asm("v_exp_f32 %0, %1" : "=v"(r) : "v"(x));
    return r;
}
__device__ __forceinline__ float rcphw(float x) {    // ~1/x via v_rcp_f32
    float r;
    asm("v_rcp_f32 %0, %1" : "=v"(r) : "v"(x));
    return r;
}

// channel -> weight-row pointer for the 384-ch concat GEMM
__device__ __forceinline__ const float* wrow(
    int gc, const float* tq, const float* tk, const float* tv,
    const float* gq, const float* gk, const float* gv,
    const float* sq, const float* sk, const float* sv) {
    if (gc < 32) return tq + (size_t)gc * 128;
    if (gc < 64) return tk + (size_t)(gc - 32) * 128;
    if (gc < 96) return tv + (size_t)(gc - 64) * 128;
    if (gc < 160) return gq + (size_t)(gc - 96) * 128;
    if (gc < 224) return gk + (size_t)(gc - 160) * 128;
    if (gc < 288) return gv + (size_t)(gc - 224) * 128;
    if (gc < 320) return sq + (size_t)(gc - 288) * 128;
    if (gc < 352) return sk + (size_t)(gc - 320) * 128;
    return sv + (size_t)(gc - 352) * 128;
}

// ---- kernel: MERGED weight conversion + pattern k/v proj + mask detect ----
// blocks 0..255: W2X/W2O bf16 conversion (geo/sem-q rows pre-scaled by
// SCALE*log2e). blocks 256..263: pattern k/v projection into fws.
// block 264: RUNTIME mask dtype detection (byte-pattern sniff) -> fws[F_FLAG].
__global__ __launch_bounds__(256) void k_prepw(
    const float* __restrict__ t_qw, const float* __restrict__ t_kw,
    const float* __restrict__ t_vw, const float* __restrict__ geo_qw,
    const float* __restrict__ geo_kw, const float* __restrict__ geo_vw,
    const float* __restrict__ sem_qw, const float* __restrict__ sem_kw,
    const float* __restrict__ sem_vw, const float* __restrict__ proj_w,
    const float* __restrict__ pattern_keys, const float* __restrict__ pat_kw,
    const float* __restrict__ pat_kb, const float* __restrict__ pat_vw,
    const float* __restrict__ pat_vb, const unsigned char* __restrict__ mask,
    bf16* __restrict__ hb, float* __restrict__ fws) {
    if (blockIdx.x < 256) {
        int gid = blockIdx.x * 256 + threadIdx.x;   // 0..65535
        if (gid < 49152) {
            int row = gid >> 7, k = gid & 127;
            const float* src = wrow(row, t_qw, t_kw, t_vw, geo_qw, geo_kw,
                                    geo_vw, sem_qw, sem_kw, sem_vw);
            float v = src[k];
            if ((row >= 96 && row < 160) || (row >= 288 && row < 320))
                v *= SCALEc * LOG2E;
            bf16 bv = f2b(v);
            hb[H_W2X + (size_t)row * 256 + 2 * k] = bv;
            hb[H_W2X + (size_t)row * 256 + 2 * k + 1] = bv;
        } else {
            int g = gid - 49152;
            hb[H_W2O + g] = f2b(proj_w[g]);
        }
    } else if (blockIdx.x < 264) {
        int idx = (blockIdx.x - 256) * 256 + threadIdx.x;   // 0..2047
        int which = idx >> 10;
        int r = idx & 1023;
        int k = r >> 6, e = r & 63;
        const float4* w = (const float4*)((which ? pat_vw : pat_kw) + (size_t)e * 128);
        const float4* pk = (const float4*)(pattern_keys + (size_t)k * 128);
        float acc = which ? pat_vb[e] : pat_kb[e];
#pragma unroll
        for (int j = 0; j < 32; ++j) {
            float4 a = pk[j], b = w[j];
            acc = fmaf(a.x, b.x, acc); acc = fmaf(a.y, b.y, acc);
            acc = fmaf(a.z, b.z, acc); acc = fmaf(a.w, b.w, acc);
        }
        fws[(which ? F_PV : F_PK) + (size_t)k * 64 + e] = acc;
    } else {
        __shared__ int s_u8, s_odd4;
        int tid = threadIdx.x;
        if (tid == 0) { s_u8 = 0; s_odd4 = 0; }
        __syncthreads();
        int u8 = 0, odd4 = 0;
        for (int i = tid * 16; i < tid * 16 + 16; ++i) {
            unsigned char v = mask[i];
            if (v && (i & 3)) u8 = 1;
            if (v && ((i & 7) == 4)) odd4 = 1;
        }
        if (u8) atomicOr(&s_u8, 1);
        if (odd4) atomicOr(&s_odd4, 1);
        __syncthreads();
        if (tid == 0) fws[F_FLAG] = s_u8 ? 0.f : (s_odd4 ? 1.f : 2.f);
    }
}

// ---- kernel: build masked-bias buffers (bf16, pre-scaled by log2e) --------
__global__ __launch_bounds__(256) void k_bias(
    const float* __restrict__ dyn, const unsigned char* __restrict__ gm,
    const unsigned char* __restrict__ sm, const float* __restrict__ fws,
    bf16* __restrict__ hb) {
    int bid = blockIdx.x;
    int tid = threadIdx.x;
    int mode = (int)fws[F_FLAG];
    if (bid < 8192) {
        int b = bid & 7;
        int inner = bid >> 3;                         // 0..1023
        size_t rem = (size_t)inner * 256 + tid;       // q*512+k, 0..262143
        size_t gid = (size_t)b * 262144 + rem;
        int mv = (mode == 0) ? (int)gm[rem]
               : (mode == 1) ? ((const int*)gm)[rem]
                             : ((const int*)gm)[2 * rem];
        hb[H_BG + gid] = f2b(mv ? -1.44e30f : dyn[gid] * LOG2E);
    } else {
        size_t sid = (size_t)(bid - 8192) * 256 + tid;
        int mv = (mode == 0) ? (int)sm[sid]
               : (mode == 1) ? ((const int*)sm)[sid]
                             : ((const int*)sm)[2 * sid];
        hb[H_BS + sid] = f2b(mv ? -1.44e30f : 0.f);
    }
}

// ---- kernel: MFMA projection GEMM X(49152x128) @ Wcat^T(128x384) ----------
// M-tile 128. X split hi/lo bf16 (K2=256); per block: all 6 N-chunks.
// LDS 64 KB, XOR-swizzled 16B granules. V outputs written TRANSPOSED per
// slice ([h][d=16][n=512]) so k_attn2m stages V^T with a straight copy.
__global__ __launch_bounds__(256, 2) void k_projx(
    const float* __restrict__ x, bf16* __restrict__ hb) {
    __shared__ short xs[128 * 256];   // 65536 B

    int tid = threadIdx.x;
    int m0 = blockIdx.x * 128;
    int b = m0 / (Tc * Nc);
    int rr = m0 - b * Tc * Nc;
    int t = rr >> 9;
    int n0 = rr & 511;

    // stage + convert X tile: fp32 -> interleaved hi/lo bf16
    for (int u = tid; u < 4096; u += 256) {
        int row = u >> 5, g = u & 31;
        float4 v = *(const float4*)(x + (size_t)(m0 + row) * 128 + g * 4);
        short8 s;
        short h0 = f2bs(v.x); s[0] = h0; s[1] = f2bs(v.x - bs2f(h0));
        short h1 = f2bs(v.y); s[2] = h1; s[3] = f2bs(v.y - bs2f(h1));
        short h2 = f2bs(v.z); s[4] = h2; s[5] = f2bs(v.z - bs2f(h2));
        short h3 = f2bs(v.w); s[6] = h3; s[7] = f2bs(v.w - bs2f(h3));
        *(short8*)&xs[row * 256 + ((g ^ (row & 7)) << 3)] = s;
    }
    __syncthreads();

    int w = tid >> 6;
    int lane = tid & 63;
    int l15 = lane & 15;
    int quad = lane >> 4;
    const bf16* w2 = hb + H_W2X;

    for (int nc = 0; nc < 6; ++nc) {
        f32x4 acc[2][4];
#pragma unroll
        for (int i = 0; i < 2; ++i)
#pragma unroll
            for (int j = 0; j < 4; ++j) acc[i][j] = (f32x4){0.f, 0.f, 0.f, 0.f};

#pragma unroll
        for (int ks = 0; ks < 8; ++ks) {
            int r0 = w * 32 + l15;
            int r1 = r0 + 16;
            short8 a0 = *(const short8*)&xs[r0 * 256 + (((ks * 4 + quad) ^ (r0 & 7)) << 3)];
            short8 a1 = *(const short8*)&xs[r1 * 256 + (((ks * 4 + quad) ^ (r1 & 7)) << 3)];
#pragma unroll
            for (int nj = 0; nj < 4; ++nj) {
                short8 bfr = *(const short8*)(w2 + (size_t)(nc * 64 + nj * 16 + l15) * 256
                                              + ks * 32 + quad * 8);
                acc[0][nj] = __builtin_amdgcn_mfma_f32_16x16x32_bf16(a0, bfr, acc[0][nj], 0, 0, 0);
                acc[1][nj] = __builtin_amdgcn_mfma_f32_16x16x32_bf16(a1, bfr, acc[1][nj], 0, 0, 0);
            }
        }
        // epilogue scatter (D: row=token via quad*4+r, col=channel via l15)
#pragma unroll
        for (int nj = 0; nj < 4; ++nj) {
            int gc = nc * 64 + nj * 16 + l15;
            int tile16 = nc * 4 + nj;
            int d = gc & 15;
#pragma unroll
            for (int i = 0; i < 2; ++i) {
                int nrow0 = n0 + w * 32 + i * 16 + quad * 4;
#pragma unroll
                for (int r = 0; r < 4; ++r) {
                    int n = nrow0 + r;
                    float v = acc[i][nj][r];
                    size_t idx;
                    if (tile16 < 6) {
                        int which = gc >> 5, hh = (gc >> 4) & 1;
                        size_t base = which == 0 ? H_TQ : which == 1 ? H_TK : H_TV;
                        idx = base + ((size_t)(b * Nc + n) * T_Hc + hh) * (Tc * HDc)
                              + t * HDc + d;
                    } else if (tile16 < 18) {
                        int r2 = gc - 96;
                        int which = r2 >> 6, hh = (r2 >> 4) & 3;
                        size_t base = which == 0 ? H_GQ : which == 1 ? H_GK : H_GV;
                        size_t sl = (((size_t)b * Tc + t) * GEO_Hc + hh) * (Nc * HDc);
                        idx = base + sl + (which == 2 ? ((size_t)d * Nc + n)
                                                      : ((size_t)n * HDc + d));
                    } else {
                        int r2 = gc - 288;
                        int which = r2 >> 5, hh = (r2 >> 4) & 1;
                        size_t base = which == 0 ? H_SQ : which == 1 ? H_SK : H_SV;
                        size_t sl = (((size_t)b * Tc + t) * SEM_Hc + hh) * (Nc * HDc);
                        idx = base + sl + (which == 2 ? ((size_t)d * Nc + n)
                                                      : ((size_t)n * HDc + d));
                    }
                    hb[idx] = f2b(v);
                }
            }
        }
    }
}

// ---- kernel: pattern-q GEMM + pattern attention fused into geo_k ----------
__global__ __launch_bounds__(256, 2) void k_projp(
    const float* __restrict__ xp, const float* __restrict__ pat_qw,
    const float* __restrict__ pat_qb, const float* __restrict__ fws,
    bf16* __restrict__ hb) {
    __shared__ float xs[64 * 132];
    __shared__ float wsh[64 * 68];
    __shared__ float pks[1024], pvs[1024], pqbs[64];

    int tid = threadIdx.x;
    int tok0 = blockIdx.x * 64;
    int ty = tid >> 4, tx = tid & 15;

    for (int u = tid; u < 2048; u += 256) {
        int row = u >> 5, f4 = u & 31;
        *(float4*)&xs[row * 132 + f4 * 4] =
            *(const float4*)(xp + (size_t)(tok0 + row) * 128 + f4 * 4);
    }
    for (int u = tid; u < 1024; u += 256) {
        pks[u] = fws[F_PK + u];
        pvs[u] = fws[F_PV + u];
    }
    if (tid < 64) pqbs[tid] = pat_qb[tid];

    float acc[4][4] = {};
    for (int kh = 0; kh < 2; ++kh) {
        __syncthreads();
        for (int u = tid; u < 1024; u += 256) {
            int row = u >> 4, f4 = u & 15;
            *(float4*)&wsh[row * 68 + f4 * 4] =
                *(const float4*)(pat_qw + (size_t)row * 128 + kh * 64 + f4 * 4);
        }
        __syncthreads();
#pragma unroll 4
        for (int kk = 0; kk < 64; kk += 4) {
            float4 a[4], b[4];
#pragma unroll
            for (int i = 0; i < 4; ++i)
                a[i] = *(const float4*)&xs[(ty + 16 * i) * 132 + kh * 64 + kk];
#pragma unroll
            for (int j = 0; j < 4; ++j)
                b[j] = *(const float4*)&wsh[(tx + 16 * j) * 68 + kk];
#pragma unroll
            for (int i = 0; i < 4; ++i)
#pragma unroll
                for (int j = 0; j < 4; ++j) {
                    acc[i][j] = fmaf(a[i].x, b[j].x, acc[i][j]);
                    acc[i][j] = fmaf(a[i].y, b[j].y, acc[i][j]);
                    acc[i][j] = fmaf(a[i].z, b[j].z, acc[i][j]);
                    acc[i][j] = fmaf(a[i].w, b[j].w, acc[i][j]);
                }
        }
    }
    __syncthreads();
    float* pqs = xs;    // reuse
    float* plogs = wsh; // reuse
#pragma unroll
    for (int i = 0; i < 4; ++i)
#pragma unroll
        for (int j = 0; j < 4; ++j)
            pqs[(ty + 16 * i) * 68 + tx + 16 * j] = acc[i][j] + pqbs[tx + 16 * j];
    __syncthreads();
    {
        int tok = tid >> 2, k4 = (tid & 3) * 4;
        for (int k = k4; k < k4 + 4; ++k) {
            float s = 0.f;
#pragma unroll 16
            for (int e = 0; e < 64; ++e)
                s = fmaf(pqs[tok * 68 + e], pks[k * 64 + e], s);
            plogs[tok * 17 + k] = s * SCALEc;
        }
    }
    __syncthreads();
    {
        int tok = tid >> 2, q = tid & 3;
        float mx = -1e30f;
        for (int k = 0; k < 16; ++k) mx = fmaxf(mx, plogs[tok * 17 + k]);
        float p[16], sum = 0.f;
        for (int k = 0; k < 16; ++k) {
            p[k] = __expf(plogs[tok * 17 + k] - mx);
            sum += p[k];
        }
        float inv = 1.f / sum;
        int token = tok0 + tok;
        int b = token / (Tc * Nc);
        int rr = token - b * Tc * Nc;
        int t = rr >> 9;
        int n = rr & 511;
        for (int cc = 0; cc < 16; ++cc) {
            int c = q * 16 + cc;
            float v = 0.f;
            for (int k = 0; k < 16; ++k) v = fmaf(p[k], pvs[k * 64 + c], v);
            v *= inv;
            size_t idx = H_GK + (((size_t)b * Tc + t) * GEO_Hc + (c >> 4)) * (Nc * HDc)
                         + n * HDc + (c & 15);
            hb[idx] = f2b(b2f(hb[idx]) + v);
        }
    }
}

// ---- kernel: temporal attention, 4 units per 256-thread block -------------
__global__ __launch_bounds__(256, 8) void k_tattn(bf16* __restrict__ hb) {
    __shared__ float q[4][192], kkv[4][192], vv[4][192], ss[4][144];
    int unit = threadIdx.x >> 6;
    int tid = threadIdx.x & 63;
    int blk = blockIdx.x * 4 + unit;
    int h = blk & 1;
    int bn = blk >> 1;
    int b = bn >> 9;
    int n = bn & 511;
    size_t base = ((size_t)(b * Nc + n) * T_Hc + h) * (Tc * HDc);

    for (int u = tid; u < 192; u += 64) {
        q[unit][u] = b2f(hb[H_TQ + base + u]);
        kkv[unit][u] = b2f(hb[H_TK + base + u]);
        vv[unit][u] = b2f(hb[H_TV + base + u]);
    }
    __syncthreads();
    for (int idx = tid; idx < 144; idx += 64) {
        int qi = idx / 12, ki = idx - qi * 12;
        float acc = 0.f;
#pragma unroll
        for (int d = 0; d < 16; ++d)
            acc = fmaf(q[unit][qi * 16 + d], kkv[unit][ki * 16 + d], acc);
        ss[unit][idx] = acc * SCALEc;
    }
    __syncthreads();
    if (tid < 12) {
        float mx = -1e30f;
        for (int ki = 0; ki < 12; ++ki) mx = fmaxf(mx, ss[unit][tid * 12 + ki]);
        float sum = 0.f;
        for (int ki = 0; ki < 12; ++ki) {
            float p = __expf(ss[unit][tid * 12 + ki] - mx);
            ss[unit][tid * 12 + ki] = p;
            sum += p;
        }
        float inv = 1.f / sum;
        for (int ki = 0; ki < 12; ++ki) ss[unit][tid * 12 + ki] *= inv;
    }
    __syncthreads();
    for (int idx = tid; idx < 192; idx += 64) {
        int qi = idx >> 4, d = idx & 15;
        float acc = 0.f;
#pragma unroll
        for (int ki = 0; ki < 12; ++ki)
            acc = fmaf(ss[unit][qi * 12 + ki], vv[unit][ki * 16 + d], acc);
        hb[H_CC + (((size_t)b * Tc + qi) * Nc + n) * Dc + h * HDc + d] = f2b(acc);
    }
}

// ---- kernel: MERGED MFMA spatial attention (geo + sem), S^T formulation ---
// v6: bf16 bias (log2e pre-scaled), exp2 logits, setprio around PV, rcp
// normalize. q-tile 64/block, grid 4608, launch_bounds(256,8), direct exp,
// shfl P-exchange, vt-only LDS (16 KB).
// Work mapping: bid&7 = b (XCD axis) -> balanced XCDs, b-local L2 read set.
__global__ __launch_bounds__(256, 8) void k_attn2m(bf16* __restrict__ hb) {
    __shared__ short vt[16 * 512];       // 16 KB, V^T rows d, swizzled granules

    int bid = blockIdx.x;                // 0..4607
    int b = bid & 7;                     // XCD-aligned batch index
    int rem = bid >> 3;                  // 0..575 per-b work id
    int m3 = rem % 3;
    int d3 = rem / 3;                    // 0..191

    int H, coff, lb;
    size_t QO, KO, VO, bstride;
    const bf16* bias0;
    if (m3 == 2) {                       // semantic work: lb in [0,192)
        H = SEM_Hc; coff = 96; QO = H_SQ; KO = H_SK; VO = H_SV;
        bias0 = hb + H_BS; bstride = 0; lb = d3;
    } else {                             // geo work: lb = 2*d3+m3 in [0,384)
        H = GEO_Hc; coff = 32; QO = H_GQ; KO = H_GK; VO = H_GV;
        bias0 = hb + H_BG; bstride = (size_t)Nc * Nc; lb = 2 * d3 + m3;
    }
    int part = lb & 7;                   // q-tile index (64 rows)
    int th = lb >> 3;
    int h = th % H;
    int t = th / H;

    size_t bth = (((size_t)b * Tc + t) * H + h) * (size_t)(Nc * HDc);
    const bf16* Qp = hb + QO + bth;
    const bf16* Kp = hb + KO + bth;
    const bf16* Vg = hb + VO + bth;      // transposed: [16][512]
    const bf16* bp = bias0 + (size_t)b * bstride;

    int tid = threadIdx.x;

    // stage V^T: straight coalesced copy, granule XOR-swizzle on LDS write
    for (int u = tid; u < 1024; u += 256) {
        int d = u >> 6, gg = u & 63;
        *(short8*)&vt[d * 512 + ((gg ^ (d & 7)) << 3)] =
            *(const short8*)(Vg + (size_t)d * 512 + gg * 8);
    }
    __syncthreads();

    int lane = tid & 63;
    int w = tid >> 6;
    int l15 = lane & 15;
    int quad = lane >> 4;
    int sw = l15 & 7;
    // shfl exchange geometry: target (l15,quad) pulls P words from lanes
    // srcA = l15 + 32*(quad&1) and srcB = srcA+16, at kt = 2*kw + (quad>>1).
    int srcA = l15 + ((lane & 16) << 1);
    int srcB = srcA + 16;
    bool hi = lane >= 32;

    union U8 { u32x4 u; short8 s; };

    int q0 = part * 64 + w * 16;
    int qg = q0 + l15;
    short8 bq = {0, 0, 0, 0, 0, 0, 0, 0};
    if (quad < 2) bq = *(const short8*)(Qp + (size_t)qg * 16 + quad * 8);

    float l_i = 0.f;
    f32x4 O = {0.f, 0.f, 0.f, 0.f};

    for (int ch = 0; ch < 4; ++ch) {
        int kabs0 = ch * 128;
        f32x4 S[8];
#pragma unroll
        for (int kt = 0; kt < 8; ++kt) {
            int kabs = kabs0 + kt * 16;
            short4 bb = *(const short4*)(bp + (size_t)qg * 512 + kabs + quad * 4);
            f32x4 c;
            c[0] = bs2f(bb.x); c[1] = bs2f(bb.y);
            c[2] = bs2f(bb.z); c[3] = bs2f(bb.w);
            short8 ak = {0, 0, 0, 0, 0, 0, 0, 0};
            if (quad < 2)
                ak = *(const short8*)(Kp + (size_t)(kabs + l15) * 16 + quad * 8);
            S[kt] = __builtin_amdgcn_mfma_f32_16x16x32_bf16(ak, bq, c, 0, 0, 0);
        }
        // logits pre-scaled by log2e -> raw v_exp_f32 (2^x); masked bias
        // = -1.44e30 -> 0. No max tracking (data bounded).
        unsigned pk2[8][2];
        float psum = 0.f;
#pragma unroll
        for (int kt = 0; kt < 8; ++kt) {
            float p0 = exp2hw(S[kt][0]);
            float p1 = exp2hw(S[kt][1]);
            float p2 = exp2hw(S[kt][2]);
            float p3 = exp2hw(S[kt][3]);
            psum += (p0 + p1) + (p2 + p3);
            pk2[kt][0] = packbf(p0, p1);
            pk2[kt][1] = packbf(p2, p3);
        }
        psum += __shfl_xor(psum, 16);
        psum += __shfl_xor(psum, 32);
        l_i += psum;
        __builtin_amdgcn_s_setprio(1);
#pragma unroll
        for (int kw = 0; kw < 4; ++kw) {
            unsigned eA0 = __shfl(pk2[2 * kw][0], srcA);
            unsigned eA1 = __shfl(pk2[2 * kw][1], srcA);
            unsigned oA0 = __shfl(pk2[2 * kw + 1][0], srcA);
            unsigned oA1 = __shfl(pk2[2 * kw + 1][1], srcA);
            unsigned eB0 = __shfl(pk2[2 * kw][0], srcB);
            unsigned eB1 = __shfl(pk2[2 * kw][1], srcB);
            unsigned oB0 = __shfl(pk2[2 * kw + 1][0], srcB);
            unsigned oB1 = __shfl(pk2[2 * kw + 1][1], srcB);
            U8 ap;
            ap.u = (u32x4){hi ? oA0 : eA0, hi ? oA1 : eA1,
                           hi ? oB0 : eB0, hi ? oB1 : eB1};
            short8 bv = *(const short8*)&vt[l15 * 512
                             + (((ch * 16 + kw * 4 + quad) ^ sw) << 3)];
            O = __builtin_amdgcn_mfma_f32_16x16x32_bf16(ap.s, bv, O, 0, 0, 0);
        }
        __builtin_amdgcn_s_setprio(0);
    }
    float li0 = __shfl(l_i, (quad << 2) | 0);
    float li1 = __shfl(l_i, (quad << 2) | 1);
    float li2 = __shfl(l_i, (quad << 2) | 2);
    float li3 = __shfl(l_i, (quad << 2) | 3);
    size_t obase = H_CC + (((size_t)b * Tc + t) * Nc + q0) * Dc + coff + h * HDc + l15;
    hb[obase + (size_t)(quad * 4 + 0) * Dc] = f2b(O[0] * rcphw(li0));
    hb[obase + (size_t)(quad * 4 + 1) * Dc] = f2b(O[1] * rcphw(li1));
    hb[obase + (size_t)(quad * 4 + 2) * Dc] = f2b(O[2] * rcphw(li2));
    hb[obase + (size_t)(quad * 4 + 3) * Dc] = f2b(O[3] * rcphw(li3));
}

// ---- kernel: MFMA output projection CC(49152x128) @ proj_w^T --------------
__global__ __launch_bounds__(256, 3) void k_outm(
    const bf16* __restrict__ hb, const float* __restrict__ proj_b,
    float* __restrict__ out) {
    __shared__ short cs[128 * 128];   // 32 KB, swizzled granules
    __shared__ float pbs[128];

    int tid = threadIdx.x;
    int m0 = blockIdx.x * 128;

    for (int u = tid; u < 2048; u += 256) {
        int row = u >> 4, g = u & 15;
        *(short8*)&cs[row * 128 + ((g ^ (row & 7)) << 3)] =
            *(const short8*)(hb + H_CC + (size_t)(m0 + row) * 128 + g * 8);
    }
    if (tid < 128) pbs[tid] = proj_b[tid];
    __syncthreads();

    int w = tid >> 6;
    int lane = tid & 63;
    int l15 = lane & 15;
    int quad = lane >> 4;
    const bf16* w2o = hb + H_W2O;

    f32x4 acc[2][8];
#pragma unroll
    for (int i = 0; i < 2; ++i)
#pragma unroll
        for (int j = 0; j < 8; ++j) acc[i][j] = (f32x4){0.f, 0.f, 0.f, 0.f};

#pragma unroll
    for (int ks = 0; ks < 4; ++ks) {
        int r0 = w * 32 + l15;
        int r1 = r0 + 16;
        short8 a0 = *(const short8*)&cs[r0 * 128 + (((ks * 4 + quad) ^ (r0 & 7)) << 3)];
        short8 a1 = *(const short8*)&cs[r1 * 128 + (((ks * 4 + quad) ^ (r1 & 7)) << 3)];
#pragma unroll
        for (int nj = 0; nj < 8; ++nj) {
            short8 bfr = *(const short8*)(w2o + (size_t)(nj * 16 + l15) * 128
                                          + ks * 32 + quad * 8);
            acc[0][nj] = __builtin_amdgcn_mfma_f32_16x16x32_bf16(a0, bfr, acc[0][nj], 0, 0, 0);
            acc[1][nj] = __builtin_amdgcn_mfma_f32_16x16x32_bf16(a1, bfr, acc[1][nj], 0, 0, 0);
        }
    }
#pragma unroll
    for (int i = 0; i < 2; ++i) {
#pragma unroll
        for (int nj = 0; nj < 8; ++nj) {
            int ch = nj * 16 + l15;
            float bias = pbs[ch];
#pragma unroll
            for (int r = 0; r < 4; ++r) {
                int token = m0 + w * 32 + i * 16 + quad * 4 + r;
                out[(size_t)token * 128 + ch] = acc[i][nj][r] + bias;
            }
        }
    }
}

extern "C" void kernel_launch(void* const* d_in, const int* in_sizes, int n_in,
                              void* d_out, int out_size, void* d_ws, size_t ws_size,
                              hipStream_t stream) {
    const float* x = (const float*)d_in[0];
    const float* xp = (const float*)d_in[1];
    const float* pattern_keys = (const float*)d_in[2];
    const float* dyn = (const float*)d_in[3];
    const void* geo_mask = d_in[4];
    const void* sem_mask = d_in[5];
    const float* t_qw = (const float*)d_in[6];
    const float* t_kw = (const float*)d_in[7];
    const float* t_vw = (const float*)d_in[8];
    const float* geo_qw = (const float*)d_in[9];
    const float* geo_kw = (const float*)d_in[10];
    const float* geo_vw = (const float*)d_in[11];
    const float* sem_qw = (const float*)d_in[12];
    const float* sem_kw = (const float*)d_in[13];
    const float* sem_vw = (const float*)d_in[14];
    const float* pat_qw = (const float*)d_in[15];
    const float* pat_qb = (const float*)d_in[16];
    const float* pat_kw = (const float*)d_in[17];
    const float* pat_kb = (const float*)d_in[18];
    const float* pat_vw = (const float*)d_in[19];
    const float* pat_vb = (const float*)d_in[20];
    const float* proj_w = (const float*)d_in[21];
    const float* proj_b = (const float*)d_in[22];

    bf16* hb = (bf16*)d_ws;
    float* fws = (float*)d_ws;

    k_prepw<<<265, 256, 0, stream>>>(t_qw, t_kw, t_vw, geo_qw, geo_kw, geo_vw,
                                     sem_qw, sem_kw, sem_vw, proj_w,
                                     pattern_keys, pat_kw, pat_kb, pat_vw,
                                     pat_vb, (const unsigned char*)geo_mask,
                                     hb, fws);
    k_projx<<<384, 256, 0, stream>>>(x, hb);
    k_projp<<<768, 256, 0, stream>>>(xp, pat_qw, pat_qb, fws, hb);
    k_tattn<<<2048, 256, 0, stream>>>(hb);
    k_bias<<<9216, 256, 0, stream>>>(dyn, (const unsigned char*)geo_mask,
                                     (const unsigned char*)sem_mask, fws, hb);
    k_attn2m<<<Bc * Tc * (GEO_Hc + SEM_Hc) * 8, 256, 0, stream>>>(hb);
    k_outm<<<384, 256, 0, stream>>>(hb, proj_b, (float*)d_out);
}